// Round 3
// baseline (836.713 us; speedup 1.0000x reference)
//
#include <hip/hip_runtime.h>

// GlobalGOCorOpt fused kernel for MI355X (gfx950) — round 3.
// B=2, NF=4096, C=256, H=W=64, HW=4096, NUM_ITER=2, NUM_BINS=10, BIN_DISP=0.5
// One block = (batch, 16-filter tile), 512 threads (8 waves), grid 512
// (2 blocks/CU -> 4 waves/SIMD). f16 MFMA 16x16x32, fp32 accum; master filter
// lives in MFMA fragment registers.

#define NFILT 4096
#define CDIM  256
#define HWDIM 4096
#define TF    16

typedef _Float16 f16;
typedef _Float16 f16x8 __attribute__((ext_vector_type(8)));
typedef float f32x4 __attribute__((ext_vector_type(4)));

// XOR swizzle within a row-major [*][ld] f16 LDS tile (ld multiple of 64):
// spreads 8 consecutive rows across 8 16-byte slots.
__device__ __forceinline__ int swz(int f, int j, int ld) {
  return f * ld + (((j >> 3) ^ (f & 7)) << 3) + (j & 7);
}

// lgkm-only barrier: DS ops pinned, global loads may stay in flight across it.
#define LGKM_BARRIER() do {                         \
    __builtin_amdgcn_sched_barrier(0x7F);           \
    asm volatile("s_waitcnt lgkmcnt(0)");           \
    __builtin_amdgcn_s_barrier();                   \
    __builtin_amdgcn_sched_barrier(0x7F);           \
  } while (0)

// ---------- kernel 0: packed map table {vp*label, vp, sigmoid(mask), 0} ----------
__global__ __launch_bounds__(256) void k_maps(
    const float* __restrict__ wl, const float* __restrict__ wsp,
    const float* __restrict__ wmk, float4* __restrict__ tbl)
{
  int i = blockIdx.x * 256 + threadIdx.x;
  if (i >= 127 * 127) return;
  int yy = i / 127, xx = i - yy * 127;
  float dy = (float)yy - 63.f, dx = (float)xx - 63.f;
  float d2 = 2.f * sqrtf(dy * dy + dx * dx);   // dist / BIN_DISP
  float l = 0.f, v = 0.f, m = 0.f;
#pragma unroll
  for (int k = 0; k < 9; ++k) {
    float t = fmaxf(1.f - fabsf(d2 - (float)k), 0.f);
    l += wl[k] * t; v += wsp[k] * t; m += wmk[k] * t;
  }
  float t9 = fminf(fmaxf(d2 - 8.f, 0.f), 1.f);
  l += wl[9] * t9; v += wsp[9] * t9; m += wmk[9] * t9;
  tbl[i] = make_float4(v * l, v, 1.f / (1.f + expf(-m)), 0.f);
}

// ---------- kernel 1: feat f32 -> f16 [b][c][yx] and transposed [b][yx][c] ----------
__global__ __launch_bounds__(256) void k_convert(
    const float* __restrict__ feat, f16* __restrict__ featc,
    f16* __restrict__ featT)
{
  __shared__ float tbuf[64][65];
  int bid = blockIdx.x;                        // 512 blocks = 2b x 4cb x 64yb
  int b = bid >> 8, cb = (bid >> 6) & 3, yb = bid & 63;
  int ty = threadIdx.x & 63, tc = threadIdx.x >> 6;
  const float* src = feat + ((size_t)b * CDIM + cb * 64) * HWDIM + yb * 64;
#pragma unroll
  for (int s = 0; s < 16; ++s) {
    int c = s * 4 + tc;
    float v = src[(size_t)c * HWDIM + ty];
    tbuf[c][ty] = v;
    featc[((size_t)b * CDIM + cb * 64 + c) * HWDIM + yb * 64 + ty] = (f16)v;
  }
  __syncthreads();
#pragma unroll
  for (int s = 0; s < 16; ++s) {
    int y = s * 4 + tc;
    featT[((size_t)b * HWDIM + yb * 64 + y) * CDIM + cb * 64 + ty] = (f16)tbuf[ty][y];
  }
}

// ---------- kernel 2: fused 2-iteration GOCor optimizer ----------
__global__ __launch_bounds__(512, 4) void k_gocor(
    const float* __restrict__ filt_g,          // [B][NF][C] f32
    const f16*  __restrict__ featc,            // [B][C][HW] f16
    const f16*  __restrict__ featT,            // [B][HW][C] f16
    const float4* __restrict__ tbl,            // [127*127] {vp*lab, vp, wm, 0}
    const float* __restrict__ lsl,
    const float* __restrict__ freg,
    unsigned short* __restrict__ sgn_ws,       // [grid][8ch][8w][64lane] sign words
    float* __restrict__ out)                   // [B][NF][C] f32
{
  __shared__ __align__(16) unsigned char smem[25600];
  f16*   filt16 = (f16*)smem;                  // [16][256] f16 swz: filt / fgrad
  f16*   mresS  = (f16*)(smem + 8192);         // [16][512] f16 swz, chunk mres
  float* redbuf = (float*)(smem + 24576);      // [8][16]
  float* anumS  = redbuf + 128;                // [16]
  float* alphaS = anumS + 16;                  // [16]

  const int tid  = threadIdx.x;
  const int w    = tid >> 6;                   // wave 0..7
  const int lane = tid & 63;
  const int llo  = lane & 15, lhi = lane >> 4;

  // XCD-aware decode: XCDs 0-3 -> batch 0, XCDs 4-7 -> batch 1.
  const int bid  = blockIdx.x;
  const int xcd  = bid & 7, slot = bid >> 3;   // slot 0..63
  const int b    = (xcd >= 4) ? 1 : 0;
  const int tile = (xcd & 3) * 64 + slot;      // 0..255
  const int f0   = tile * TF;
  const int py   = f0 >> 6, pxb = f0 & 63;

  const float sl = expf(lsl[0]);
  const float fr = freg[0];
  const float rw = fmaxf(fr * fr, 1e-10f);     // MIN_FILTER_REG^2

  const f16* fT = featT + (size_t)b * HWDIM * CDIM;
  const f16* fC = featc + (size_t)b * CDIM * HWDIM;
  unsigned short* sgnB = sgn_ws + (size_t)bid * 4096;

  // Master filter in GEMM2-fragment registers: (fl, c) owner.
  // fl = lhi*4 + r ; c = w*32 + nj*16 + llo
  f32x4 fm[2];
  {
    const float* fg0 = filt_g + ((size_t)b * NFILT + f0) * CDIM;
#pragma unroll
    for (int nj = 0; nj < 2; ++nj)
#pragma unroll
      for (int r = 0; r < 4; ++r) {
        const int fl = lhi * 4 + r;
        const int c  = w * 32 + nj * 16 + llo;
        float v = fg0[fl * CDIM + c];
        fm[nj][r] = v;
        filt16[swz(fl, c, 256)] = (f16)v;
      }
  }
  __syncthreads();

  for (int it = 0; it < 2; ++it) {
    f32x4 facc[2];                             // fgrad_loss -> fgrad fragments
#pragma unroll
    for (int nj = 0; nj < 2; ++nj)
      facc[nj] = (f32x4){0.f, 0.f, 0.f, 0.f};

    // ================= pass 1: scores -> mres -> fgrad_loss =================
    for (int ch = 0; ch < 8; ++ch) {           // 8 chunks of 512 yx (8 y-rows)
      // ---- GEMM1: scores[f][yx]; wave w owns y-row ch*8+w (64 x)
      f32x4 sc[4];
#pragma unroll
      for (int ni = 0; ni < 4; ++ni)
        sc[ni] = (f32x4){0.f, 0.f, 0.f, 0.f};
      {
        const f16* Bp = fT + (size_t)(ch * 512 + w * 64) * CDIM;
#pragma unroll
        for (int k = 0; k < 8; ++k) {
          const int ko = k * 32 + lhi * 8;
          f16x8 a0 = *(const f16x8*)&filt16[swz(llo, ko, 256)];
#pragma unroll
          for (int ni = 0; ni < 4; ++ni) {
            f16x8 bv = *(const f16x8*)&Bp[(ni * 16 + llo) * CDIM + ko];
            sc[ni] = __builtin_amdgcn_mfma_f32_16x16x32_f16(a0, bv, sc[ni], 0, 0, 0);
          }
        }
      }
      // ---- epilogue: mres = dct*(act - vp*lab); pack sign bits
      {
        const int iy = 63 - py + ch * 8 + w;
        const int tb = iy * 127 + 63 - pxb;
        unsigned int sbits = 0u;
#pragma unroll
        for (int ni = 0; ni < 4; ++ni)
#pragma unroll
          for (int r = 0; r < 4; ++r) {
            const int fl = lhi * 4 + r;
            const int x  = ni * 16 + llo;
            const float4 tv = tbl[tb - fl + x];
            const float s  = sc[ni][r];
            const float q  = 0.5f * tv.y;           // 0.5*vp
            const float qa = q * tv.z;              // 0.5*vp*a
            const float h1 = q - qa, h2 = q + qa;
            const float sg0 = (s > 0.f) ? 1.f : ((s < 0.f) ? -1.f : 0.f);
            const float act = h1 * fabsf(s) + h2 * s;
            const float dct = h1 * sg0 + h2;
            const float mr  = dct * (act - tv.x);   // tv.x = vp*label
            mresS[swz(fl, w * 64 + x, 512)] = (f16)mr;
            sbits |= (s > 0.f ? 1u : 0u) << (ni * 4 + r);
          }
        sgnB[(ch * 8 + w) * 64 + lane] = (unsigned short)sbits;
      }
      LGKM_BARRIER();
      // ---- GEMM2: facc[f][c] += mres[f][yx] * feat[c][yx] over this chunk
      {
#pragma unroll
        for (int k = 0; k < 16; ++k) {
          const int ko = k * 32 + lhi * 8;
          f16x8 a0 = *(const f16x8*)&mresS[swz(llo, ko, 512)];
#pragma unroll
          for (int nj = 0; nj < 2; ++nj) {
            const f16* bp = fC + (size_t)(w * 32 + nj * 16 + llo) * HWDIM + ch * 512 + ko;
            f16x8 bv = *(const f16x8*)bp;
            facc[nj] = __builtin_amdgcn_mfma_f32_16x16x32_f16(a0, bv, facc[nj], 0, 0, 0);
          }
        }
      }
      LGKM_BARRIER();
    }

    // ================= fgrad = rw*filt + loss; alpha_num =================
    float nump[4];
#pragma unroll
    for (int i = 0; i < 4; ++i) nump[i] = 0.f;
#pragma unroll
    for (int nj = 0; nj < 2; ++nj)
#pragma unroll
      for (int r = 0; r < 4; ++r) {
        const int fl = lhi * 4 + r;
        const int c  = w * 32 + nj * 16 + llo;
        float fg = rw * fm[nj][r] + facc[nj][r];
        facc[nj][r] = fg;                      // facc now = fgrad (fp32)
        filt16[swz(fl, c, 256)] = (f16)fg;     // A-operand for GEMM3
        nump[r] += fg * fg;
      }
#pragma unroll
    for (int i = 0; i < 4; ++i) {
      float v = nump[i];
      v += __shfl_xor(v, 1); v += __shfl_xor(v, 2);
      v += __shfl_xor(v, 4); v += __shfl_xor(v, 8);
      nump[i] = v;
    }
    __syncthreads();                           // filt16 writes visible to all
    if (llo == 0) {
#pragma unroll
      for (int i = 0; i < 4; ++i)
        redbuf[w * 16 + lhi * 4 + i] = nump[i];
    }
    __syncthreads();
    if (tid < 16) {
      float s = 0.f;
#pragma unroll
      for (int j = 0; j < 8; ++j) s += redbuf[j * 16 + tid];
      anumS[tid] = s;
    }

    // ================= pass 2: sg -> den_res -> alpha_den =================
    float dacc[4];
#pragma unroll
    for (int i = 0; i < 4; ++i) dacc[i] = 0.f;
    for (int ch = 0; ch < 8; ++ch) {
      f32x4 sg[4];
#pragma unroll
      for (int ni = 0; ni < 4; ++ni)
        sg[ni] = (f32x4){0.f, 0.f, 0.f, 0.f};
      {
        const f16* Bp = fT + (size_t)(ch * 512 + w * 64) * CDIM;
#pragma unroll
        for (int k = 0; k < 8; ++k) {
          const int ko = k * 32 + lhi * 8;
          f16x8 a0 = *(const f16x8*)&filt16[swz(llo, ko, 256)];   // = fgrad
#pragma unroll
          for (int ni = 0; ni < 4; ++ni) {
            f16x8 bv = *(const f16x8*)&Bp[(ni * 16 + llo) * CDIM + ko];
            sg[ni] = __builtin_amdgcn_mfma_f32_16x16x32_f16(a0, bv, sg[ni], 0, 0, 0);
          }
        }
      }
      {
        const unsigned int sbits = sgnB[(ch * 8 + w) * 64 + lane];
        const int iy = 63 - py + ch * 8 + w;
        const int tb = iy * 127 + 63 - pxb;
#pragma unroll
        for (int ni = 0; ni < 4; ++ni)
#pragma unroll
          for (int r = 0; r < 4; ++r) {
            const int fl = lhi * 4 + r;
            const int x  = ni * 16 + llo;
            const float4 tv = tbl[tb - fl + x];
            const float q  = 0.5f * tv.y;
            const float qa = q * tv.z;
            const float h1 = q - qa, h2 = q + qa;
            const float sg0 = ((sbits >> (ni * 4 + r)) & 1u) ? 1.f : -1.f;
            const float dct = h1 * sg0 + h2;
            const float dr  = dct * sg[ni][r];
            dacc[r] += dr * dr;
          }
      }
    }
#pragma unroll
    for (int i = 0; i < 4; ++i) {
      float v = dacc[i];
      v += __shfl_xor(v, 1); v += __shfl_xor(v, 2);
      v += __shfl_xor(v, 4); v += __shfl_xor(v, 8);
      dacc[i] = v;
    }
    __syncthreads();
    if (llo == 0) {
#pragma unroll
      for (int i = 0; i < 4; ++i)
        redbuf[w * 16 + lhi * 4 + i] = dacc[i];
    }
    __syncthreads();
    if (tid < 16) {
      float num = anumS[tid];
      float den = 0.f;
#pragma unroll
      for (int j = 0; j < 8; ++j) den += redbuf[j * 16 + tid];
      alphaS[tid] = num / fmaxf(den + rw * num, 1e-8f);  // STEPLEN_REG = 0
    }
    __syncthreads();
    // ================= update: filt -= sl*alpha*fgrad =================
#pragma unroll
    for (int nj = 0; nj < 2; ++nj)
#pragma unroll
      for (int r = 0; r < 4; ++r) {
        const int fl = lhi * 4 + r;
        const int c  = w * 32 + nj * 16 + llo;
        const float nv = fm[nj][r] - sl * alphaS[fl] * facc[nj][r];
        fm[nj][r] = nv;
        if (it == 0) filt16[swz(fl, c, 256)] = (f16)nv;
      }
    if (it == 0) __syncthreads();
  }

  // ================= output =================
  {
    float* og = out + ((size_t)b * NFILT + f0) * CDIM;
#pragma unroll
    for (int nj = 0; nj < 2; ++nj)
#pragma unroll
      for (int r = 0; r < 4; ++r) {
        const int fl = lhi * 4 + r;
        const int c  = w * 32 + nj * 16 + llo;
        og[fl * CDIM + c] = fm[nj][r];
      }
  }
}

extern "C" void kernel_launch(void* const* d_in, const int* in_sizes, int n_in,
                              void* d_out, int out_size, void* d_ws, size_t ws_size,
                              hipStream_t stream) {
  (void)in_sizes; (void)n_in; (void)out_size; (void)ws_size;
  const float* filt  = (const float*)d_in[0];   // filter_map [2][4096][256]
  const float* rfeat = (const float*)d_in[1];   // reference_feat [1][2][256][64][64]
  // d_in[2] query_feat: unused by the reference
  const float* wl  = (const float*)d_in[3];
  const float* wsp = (const float*)d_in[4];
  const float* wmk = (const float*)d_in[5];
  const float* lsl = (const float*)d_in[6];
  const float* fre = (const float*)d_in[7];

  char* ws = (char*)d_ws;
  float4* tbl = (float4*)(ws + 0);              // 127*127*16 B (pad to 256K)
  f16* featc  = (f16*)(ws + 262144);            // 4 MB
  f16* featT  = (f16*)(ws + 4456448);           // 4 MB
  unsigned short* sgn = (unsigned short*)(ws + 8650752);  // 512*4096*2 = 4 MB
  float* out = (float*)d_out;

  k_maps<<<64, 256, 0, stream>>>(wl, wsp, wmk, tbl);
  k_convert<<<512, 256, 0, stream>>>(rfeat, featc, featT);
  k_gocor<<<512, 512, 0, stream>>>(filt, featc, featT, tbl, lsl, fre, sgn, out);
}

// Round 4
// 704.063 us; speedup vs baseline: 1.1884x; 1.1884x over previous
//
#include <hip/hip_runtime.h>

// GlobalGOCorOpt fused kernel for MI355X (gfx950) — round 4.
// B=2, NF=4096, C=256, H=W=64, HW=4096, NUM_ITER=2, NUM_BINS=10, BIN_DISP=0.5
// One block = (batch, 32-filter tile), 512 threads (8 waves), grid 256
// (1 block/CU, 2 waves/SIMD, VGPR budget 256). f16 MFMA 16x16x32, fp32 accum.
// Pass 1 is software-pipelined at chunk level: GEMM2(ch-1) || GEMM1(ch) with
// double-buffered mres in LDS, ONE lgkm-only barrier per chunk, and the next
// chunk's B-fragments issued BEFORE the barrier so they fly across it.

#define NFILT 4096
#define CDIM  256
#define HWDIM 4096
#define TF    32

typedef _Float16 f16;
typedef _Float16 f16x8 __attribute__((ext_vector_type(8)));
typedef float f32x4 __attribute__((ext_vector_type(4)));

// XOR swizzle within a row-major [*][256] f16 LDS tile.
__device__ __forceinline__ int swz(int f, int j) {
  return f * 256 + (((j >> 3) ^ (f & 7)) << 3) + (j & 7);
}

// lgkm-only barrier: DS ops pinned (not in mask), VMEM may cross in flight.
#define LGKM_BARRIER() do {                         \
    __builtin_amdgcn_sched_barrier(0x7F);           \
    asm volatile("s_waitcnt lgkmcnt(0)");           \
    __builtin_amdgcn_s_barrier();                   \
    __builtin_amdgcn_sched_barrier(0x7F);           \
  } while (0)

// ---------- kernel 0: packed map table {vp*label, vp, sigmoid(mask), 0} ----------
__global__ __launch_bounds__(256) void k_maps(
    const float* __restrict__ wl, const float* __restrict__ wsp,
    const float* __restrict__ wmk, float4* __restrict__ tbl)
{
  int i = blockIdx.x * 256 + threadIdx.x;
  if (i >= 127 * 127) return;
  int yy = i / 127, xx = i - yy * 127;
  float dy = (float)yy - 63.f, dx = (float)xx - 63.f;
  float d2 = 2.f * sqrtf(dy * dy + dx * dx);   // dist / BIN_DISP
  float l = 0.f, v = 0.f, m = 0.f;
#pragma unroll
  for (int k = 0; k < 9; ++k) {
    float t = fmaxf(1.f - fabsf(d2 - (float)k), 0.f);
    l += wl[k] * t; v += wsp[k] * t; m += wmk[k] * t;
  }
  float t9 = fminf(fmaxf(d2 - 8.f, 0.f), 1.f);
  l += wl[9] * t9; v += wsp[9] * t9; m += wmk[9] * t9;
  tbl[i] = make_float4(v * l, v, 1.f / (1.f + expf(-m)), 0.f);
}

// ---------- kernel 1: feat f32 -> f16 [b][c][yx] and transposed [b][yx][c] ----------
__global__ __launch_bounds__(256) void k_convert(
    const float* __restrict__ feat, f16* __restrict__ featc,
    f16* __restrict__ featT)
{
  __shared__ float tbuf[64][65];
  int bid = blockIdx.x;                        // 512 blocks = 2b x 4cb x 64yb
  int b = bid >> 8, cb = (bid >> 6) & 3, yb = bid & 63;
  int ty = threadIdx.x & 63, tc = threadIdx.x >> 6;
  const float* src = feat + ((size_t)b * CDIM + cb * 64) * HWDIM + yb * 64;
#pragma unroll
  for (int s = 0; s < 16; ++s) {
    int c = s * 4 + tc;
    float v = src[(size_t)c * HWDIM + ty];
    tbuf[c][ty] = v;
    featc[((size_t)b * CDIM + cb * 64 + c) * HWDIM + yb * 64 + ty] = (f16)v;
  }
  __syncthreads();
#pragma unroll
  for (int s = 0; s < 16; ++s) {
    int y = s * 4 + tc;
    featT[((size_t)b * HWDIM + yb * 64 + y) * CDIM + cb * 64 + ty] = (f16)tbuf[ty][y];
  }
}

// ---------- kernel 2: fused 2-iteration GOCor optimizer ----------
__global__ __launch_bounds__(512, 2) void k_gocor(
    const float* __restrict__ filt_g,          // [B][NF][C] f32
    const f16*  __restrict__ featc,            // [B][C][HW] f16
    const f16*  __restrict__ featT,            // [B][HW][C] f16
    const float4* __restrict__ tbl,            // [127*127] {vp*lab, vp, wm, 0}
    const float* __restrict__ lsl,
    const float* __restrict__ freg,
    unsigned short* __restrict__ sgn_ws,       // [grid][16ch][8w][64lane]
    float* __restrict__ out)                   // [B][NF][C] f32
{
  __shared__ __align__(16) unsigned char smem[50688];
  f16*   filt16 = (f16*)smem;                  // [32][256] swz: filt / fgrad
  f16*   mres0  = (f16*)(smem + 16384);        // [32][256] swz, chunk mres buf0
  f16*   mres1  = (f16*)(smem + 32768);        // buf1
  float* redbuf = (float*)(smem + 49152);      // [8][32]
  float* anumS  = redbuf + 256;                // [32]
  float* alphaS = anumS + 32;                  // [32]

  const int tid  = threadIdx.x;
  const int w    = tid >> 6;                   // wave 0..7
  const int lane = tid & 63;
  const int llo  = lane & 15, lhi = lane >> 4;

  // XCD-aware decode: XCDs 0-3 -> batch 0, XCDs 4-7 -> batch 1.
  const int bid  = blockIdx.x;
  const int xcd  = bid & 7, slot = bid >> 3;   // slot 0..31
  const int b    = (xcd >= 4) ? 1 : 0;
  const int tile = (xcd & 3) * 32 + slot;      // 0..127
  const int f0   = tile * TF;
  const int py   = f0 >> 6, pxb = f0 & 63;

  const float sl = expf(lsl[0]);
  const float fr = freg[0];
  const float rw = fmaxf(fr * fr, 1e-10f);     // MIN_FILTER_REG^2

  const f16* fT = featT + (size_t)b * HWDIM * CDIM;
  const f16* fC = featc + (size_t)b * CDIM * HWDIM;
  unsigned short* sgnB = sgn_ws + (size_t)bid * 8192;

  // chunk geometry: chunk = 256 yx (4 y-rows); wave w owns yx_local
  // [w*32, w*32+32): y_local = w>>1, x-half = (w&1)*32.
  // GEMM2 c-slice per wave: c in [w*32, w*32+32).

  // Master filter in GEMM2-fragment registers: fl = mi*16+lhi*4+r,
  // c = w*32 + nj*16 + llo.
  f32x4 fm[2][2];
  {
    const float* fg0 = filt_g + ((size_t)b * NFILT + f0) * CDIM;
#pragma unroll
    for (int mi = 0; mi < 2; ++mi)
#pragma unroll
      for (int nj = 0; nj < 2; ++nj)
#pragma unroll
        for (int r = 0; r < 4; ++r) {
          const int fl = mi * 16 + lhi * 4 + r;
          const int c  = w * 32 + nj * 16 + llo;
          float v = fg0[fl * CDIM + c];
          fm[mi][nj][r] = v;
          filt16[swz(fl, c)] = (f16)v;
        }
  }
  __syncthreads();

  // ---- helpers ----
  auto load_bT = [&](f16x8 (&bb)[8][2], int ch) {       // featT B (GEMM1/pass2)
#pragma unroll
    for (int k = 0; k < 8; ++k)
#pragma unroll
      for (int ni = 0; ni < 2; ++ni)
        bb[k][ni] = *(const f16x8*)&fT[(size_t)(ch * 256 + w * 32 + ni * 16 + llo) * CDIM
                                       + k * 32 + lhi * 8];
  };
  auto load_bC = [&](f16x8 (&bb)[8][2], int ch) {       // featc B (GEMM2)
#pragma unroll
    for (int k = 0; k < 8; ++k)
#pragma unroll
      for (int nj = 0; nj < 2; ++nj)
        bb[k][nj] = *(const f16x8*)&fC[(size_t)(w * 32 + nj * 16 + llo) * HWDIM
                                       + ch * 256 + k * 32 + lhi * 8];
  };
  auto gemm1 = [&](const f16x8 (&bb)[8][2], f32x4 (&sc)[2][2], const f16* A) {
#pragma unroll
    for (int k = 0; k < 8; ++k) {
      const int ko = k * 32 + lhi * 8;
      f16x8 a0 = *(const f16x8*)&A[swz(llo, ko)];
      f16x8 a1 = *(const f16x8*)&A[swz(16 + llo, ko)];
#pragma unroll
      for (int ni = 0; ni < 2; ++ni) {
        sc[0][ni] = __builtin_amdgcn_mfma_f32_16x16x32_f16(a0, bb[k][ni], sc[0][ni], 0, 0, 0);
        sc[1][ni] = __builtin_amdgcn_mfma_f32_16x16x32_f16(a1, bb[k][ni], sc[1][ni], 0, 0, 0);
      }
    }
  };
  auto gemm2 = [&](const f16x8 (&bb)[8][2], f32x4 (&acc)[2][2], const f16* mp) {
#pragma unroll
    for (int k = 0; k < 8; ++k) {
      const int ko = k * 32 + lhi * 8;
      f16x8 a0 = *(const f16x8*)&mp[swz(llo, ko)];
      f16x8 a1 = *(const f16x8*)&mp[swz(16 + llo, ko)];
#pragma unroll
      for (int nj = 0; nj < 2; ++nj) {
        acc[0][nj] = __builtin_amdgcn_mfma_f32_16x16x32_f16(a0, bb[k][nj], acc[0][nj], 0, 0, 0);
        acc[1][nj] = __builtin_amdgcn_mfma_f32_16x16x32_f16(a1, bb[k][nj], acc[1][nj], 0, 0, 0);
      }
    }
  };
  auto epilogue1 = [&](const f32x4 (&sc)[2][2], int ch, f16* mq) {
    const int iy = 63 - py + ch * 4 + (w >> 1);
    const int tb = iy * 127 + 63 - pxb;
    unsigned int sbits = 0u;
#pragma unroll
    for (int mi = 0; mi < 2; ++mi)
#pragma unroll
      for (int ni = 0; ni < 2; ++ni)
#pragma unroll
        for (int r = 0; r < 4; ++r) {
          const int fl = mi * 16 + lhi * 4 + r;
          const int x  = (w & 1) * 32 + ni * 16 + llo;
          const float4 tv = tbl[tb - fl + x];
          const float s  = sc[mi][ni][r];
          const float q  = 0.5f * tv.y;              // 0.5*vp
          const float qa = q * tv.z;                 // 0.5*vp*a
          const float h1 = q - qa, h2 = q + qa;
          const float sg0 = (s > 0.f) ? 1.f : ((s < 0.f) ? -1.f : 0.f);
          const float act = h1 * fabsf(s) + h2 * s;
          const float dct = h1 * sg0 + h2;
          const float mr  = dct * (act - tv.x);      // tv.x = vp*label
          mq[swz(fl, w * 32 + ni * 16 + llo)] = (f16)mr;
          sbits |= (s > 0.f ? 1u : 0u) << (mi * 8 + ni * 4 + r);
        }
    sgnB[(ch * 8 + w) * 64 + lane] = (unsigned short)sbits;
  };

  for (int it = 0; it < 2; ++it) {
    f32x4 facc[2][2];
#pragma unroll
    for (int mi = 0; mi < 2; ++mi)
#pragma unroll
      for (int nj = 0; nj < 2; ++nj)
        facc[mi][nj] = (f32x4){0.f, 0.f, 0.f, 0.f};

    // ================= pass 1: pipelined scores->mres->fgrad_loss =========
    f16x8 b1[8][2], b2[8][2];
    {
      // prologue: chunk 0
      load_bT(b1, 0);
      f32x4 sc[2][2] = {};
      gemm1(b1, sc, filt16);
      epilogue1(sc, 0, mres0);
      load_bC(b2, 0);                          // next GEMM2's B, flies over bar
      load_bT(b1, 1);                          // next GEMM1's B
      LGKM_BARRIER();
    }
#pragma unroll 1
    for (int ch = 1; ch < 15; ++ch) {
      const f16* mp = (ch & 1) ? mres0 : mres1;    // holds mres(ch-1)
      f16*       mq = (ch & 1) ? mres1 : mres0;    // receives mres(ch)
      gemm2(b2, facc, mp);
      f32x4 sc[2][2] = {};
      gemm1(b1, sc, filt16);
      epilogue1(sc, ch, mq);
      load_bC(b2, ch);                         // issued before barrier
      load_bT(b1, ch + 1);
      LGKM_BARRIER();
    }
    {
      // ch = 15
      gemm2(b2, facc, mres0);                  // mres(14) in buf0
      f32x4 sc[2][2] = {};
      gemm1(b1, sc, filt16);
      epilogue1(sc, 15, mres1);
      load_bC(b2, 15);
      LGKM_BARRIER();
      gemm2(b2, facc, mres1);                  // tail: mres(15)
    }

    // ================= fgrad = rw*filt + loss; alpha_num =================
    float nump[8];
#pragma unroll
    for (int i = 0; i < 8; ++i) nump[i] = 0.f;
#pragma unroll
    for (int mi = 0; mi < 2; ++mi)
#pragma unroll
      for (int nj = 0; nj < 2; ++nj)
#pragma unroll
        for (int r = 0; r < 4; ++r) {
          const int fl = mi * 16 + lhi * 4 + r;
          const int c  = w * 32 + nj * 16 + llo;
          float fg = rw * fm[mi][nj][r] + facc[mi][nj][r];
          facc[mi][nj][r] = fg;                // facc now = fgrad (fp32)
          filt16[swz(fl, c)] = (f16)fg;        // A-operand for GEMM3
          nump[mi * 4 + r] += fg * fg;
        }
#pragma unroll
    for (int i = 0; i < 8; ++i) {
      float v = nump[i];
      v += __shfl_xor(v, 1); v += __shfl_xor(v, 2);
      v += __shfl_xor(v, 4); v += __shfl_xor(v, 8);
      nump[i] = v;
    }
    __syncthreads();
    if (llo == 0) {
#pragma unroll
      for (int i = 0; i < 8; ++i) {
        const int fl = (i >> 2) * 16 + lhi * 4 + (i & 3);
        redbuf[w * 32 + fl] = nump[i];
      }
    }
    __syncthreads();
    if (tid < 32) {
      float s = 0.f;
#pragma unroll
      for (int j = 0; j < 8; ++j) s += redbuf[j * 32 + tid];
      anumS[tid] = s;
    }

    // ================= pass 2: sg -> den_res -> alpha_den =================
    float dacc[8];
#pragma unroll
    for (int i = 0; i < 8; ++i) dacc[i] = 0.f;
    auto pass2_chunk = [&](const f16x8 (&bb)[8][2], int ch) {
      f32x4 sg[2][2] = {};
      gemm1(bb, sg, filt16);                   // A = fgrad
      const unsigned int sbits = sgnB[(ch * 8 + w) * 64 + lane];
      const int iy = 63 - py + ch * 4 + (w >> 1);
      const int tb = iy * 127 + 63 - pxb;
#pragma unroll
      for (int mi = 0; mi < 2; ++mi)
#pragma unroll
        for (int ni = 0; ni < 2; ++ni)
#pragma unroll
          for (int r = 0; r < 4; ++r) {
            const int fl = mi * 16 + lhi * 4 + r;
            const int x  = (w & 1) * 32 + ni * 16 + llo;
            const float4 tv = tbl[tb - fl + x];
            const float q  = 0.5f * tv.y;
            const float qa = q * tv.z;
            const float h1 = q - qa, h2 = q + qa;
            const float sg0 = ((sbits >> (mi * 8 + ni * 4 + r)) & 1u) ? 1.f : -1.f;
            const float dct = h1 * sg0 + h2;
            const float dr  = dct * sg[mi][ni][r];
            dacc[mi * 4 + r] += dr * dr;
          }
    };
    load_bT(b1, 0);
#pragma unroll 1
    for (int cc = 0; cc < 16; cc += 2) {
      load_bT(b2, cc + 1);
      pass2_chunk(b1, cc);
      if (cc + 2 < 16) load_bT(b1, cc + 2);
      pass2_chunk(b2, cc + 1);
    }
#pragma unroll
    for (int i = 0; i < 8; ++i) {
      float v = dacc[i];
      v += __shfl_xor(v, 1); v += __shfl_xor(v, 2);
      v += __shfl_xor(v, 4); v += __shfl_xor(v, 8);
      dacc[i] = v;
    }
    __syncthreads();
    if (llo == 0) {
#pragma unroll
      for (int i = 0; i < 8; ++i) {
        const int fl = (i >> 2) * 16 + lhi * 4 + (i & 3);
        redbuf[w * 32 + fl] = dacc[i];
      }
    }
    __syncthreads();
    if (tid < 32) {
      float num = anumS[tid];
      float den = 0.f;
#pragma unroll
      for (int j = 0; j < 8; ++j) den += redbuf[j * 32 + tid];
      alphaS[tid] = num / fmaxf(den + rw * num, 1e-8f);  // STEPLEN_REG = 0
    }
    __syncthreads();
    // ================= update: filt -= sl*alpha*fgrad =================
#pragma unroll
    for (int mi = 0; mi < 2; ++mi)
#pragma unroll
      for (int nj = 0; nj < 2; ++nj)
#pragma unroll
        for (int r = 0; r < 4; ++r) {
          const int fl = mi * 16 + lhi * 4 + r;
          const int c  = w * 32 + nj * 16 + llo;
          const float nv = fm[mi][nj][r] - sl * alphaS[fl] * facc[mi][nj][r];
          fm[mi][nj][r] = nv;
          if (it == 0) filt16[swz(fl, c)] = (f16)nv;
        }
    if (it == 0) __syncthreads();
  }

  // ================= output =================
  {
    float* og = out + ((size_t)b * NFILT + f0) * CDIM;
#pragma unroll
    for (int mi = 0; mi < 2; ++mi)
#pragma unroll
      for (int nj = 0; nj < 2; ++nj)
#pragma unroll
        for (int r = 0; r < 4; ++r) {
          const int fl = mi * 16 + lhi * 4 + r;
          const int c  = w * 32 + nj * 16 + llo;
          og[fl * CDIM + c] = fm[mi][nj][r];
        }
  }
}

extern "C" void kernel_launch(void* const* d_in, const int* in_sizes, int n_in,
                              void* d_out, int out_size, void* d_ws, size_t ws_size,
                              hipStream_t stream) {
  (void)in_sizes; (void)n_in; (void)out_size; (void)ws_size;
  const float* filt  = (const float*)d_in[0];   // filter_map [2][4096][256]
  const float* rfeat = (const float*)d_in[1];   // reference_feat [1][2][256][64][64]
  // d_in[2] query_feat: unused by the reference
  const float* wl  = (const float*)d_in[3];
  const float* wsp = (const float*)d_in[4];
  const float* wmk = (const float*)d_in[5];
  const float* lsl = (const float*)d_in[6];
  const float* fre = (const float*)d_in[7];

  char* ws = (char*)d_ws;
  float4* tbl = (float4*)(ws + 0);              // 127*127*16 B (pad to 256K)
  f16* featc  = (f16*)(ws + 262144);            // 4 MB
  f16* featT  = (f16*)(ws + 4456448);           // 4 MB
  unsigned short* sgn = (unsigned short*)(ws + 8650752);  // 256*8192*2 = 4 MB
  float* out = (float*)d_out;

  k_maps<<<64, 256, 0, stream>>>(wl, wsp, wmk, tbl);
  k_convert<<<512, 256, 0, stream>>>(rfeat, featc, featT);
  k_gocor<<<256, 512, 0, stream>>>(filt, featc, featT, tbl, lsl, fre, sgn, out);
}